// Round 2
// baseline (6627.078 us; speedup 1.0000x reference)
//
#include <hip/hip_runtime.h>
#include <math.h>

// BatchSpectralLoss: out = lambda_max(A^T A), A = 8192x4096 fp32 (k==1).
// Lanczos with a FUSED one-pass B-matvec: w = A^T(Av) computed reading A once
// (per-row contribution w += (A_r . v) * A_r). Residuals kept unnormalized;
// normalization folded into the consumers, so each Lanczos step is exactly
// 2 dispatches (bmv + finish). Tridiagonal solved by Sturm bisection (1 wave).
//
// ws float layout:
//   r buffers : ws + {0, 4096, 8192}   rotating Lanczos residuals (unnormalized)
//   slots     : ws + 12288 .. +12416
//     slots[j]      = alpha_j                (j = 1..T, filled by bmv)
//     slots[64 + j] = norm2[j] = ||r_j||^2   (= beta_{j-1}^2; [64],[65] preset 1)

#define M_ROWS 8192
#define N_COLS 4096
#define T_STEPS 30
#define BMV_BLOCKS 512
#define ROWS_PER_BLOCK 16   // 4 waves x 4 passes

__global__ __launch_bounds__(256) void init_kernel(float* __restrict__ ws) {
    int i = blockIdx.x * 256 + threadIdx.x;   // 0..4095
    float* r1 = ws;           // step-1 residual (unit vector)
    float* r0 = ws + 4096;    // "r_0" = zeros
    float* wt = ws + 8192;    // step-1 w-target, must be zero
    float* slots = ws + 12288;
    unsigned h = (unsigned)i * 2654435761u;
    h ^= h >> 16; h *= 2246822519u; h ^= h >> 13;
    r1[i] = (h & 1u) ? 0.015625f : -0.015625f;   // +-1/64, unit norm
    r0[i] = 0.f;
    wt[i] = 0.f;
    if (i < 128) slots[i] = (i == 64 || i == 65) ? 1.f : 0.f;
}

// One-pass w += A^T (A v);  alpha_j += ||A v||^2.  v = r * rsqrt(norm2[j]).
// 512 blocks x 256 thr (4 waves); wave handles 4 rows sequentially.
__global__ __launch_bounds__(256, 4) void bmv_kernel(const float* __restrict__ A,
                                                     const float* __restrict__ r,
                                                     float* __restrict__ w,
                                                     float* __restrict__ slots,
                                                     int j) {
    __shared__ float v_s[N_COLS];
    __shared__ float w_s[N_COLS];   // swizzled: w_s[k*1024 + c4] = w[c4*4 + k]
    int tid = threadIdx.x, lane = tid & 63, wv = tid >> 6;
    float inv = rsqrtf(fmaxf(slots[64 + j], 1e-30f));
    for (int i = tid; i < N_COLS; i += 256) { v_s[i] = r[i] * inv; w_s[i] = 0.f; }
    __syncthreads();
    float s2 = 0.f;
#pragma unroll 1
    for (int pass = 0; pass < 4; ++pass) {
        int row = blockIdx.x * ROWS_PER_BLOCK + pass * 4 + wv;
        const float4* A4 = (const float4*)A + (size_t)row * (N_COLS / 4);
        const float4* v4 = (const float4*)v_s;
        float4 a[16];
#pragma unroll
        for (int it = 0; it < 16; ++it) a[it] = A4[it * 64 + lane];
        float s = 0.f;
#pragma unroll
        for (int it = 0; it < 16; ++it) {
            float4 b = v4[it * 64 + lane];
            s += a[it].x * b.x + a[it].y * b.y + a[it].z * b.z + a[it].w * b.w;
        }
#pragma unroll
        for (int off = 32; off > 0; off >>= 1) s += __shfl_xor(s, off);
        s2 += s * s;
        // conflict-free LDS accumulation (lanes stride 4B per component plane)
#pragma unroll
        for (int it = 0; it < 16; ++it) {
            int idx = it * 64 + lane;
            atomicAdd(&w_s[0 * 1024 + idx], s * a[it].x);
            atomicAdd(&w_s[1 * 1024 + idx], s * a[it].y);
            atomicAdd(&w_s[2 * 1024 + idx], s * a[it].z);
            atomicAdd(&w_s[3 * 1024 + idx], s * a[it].w);
        }
    }
    __shared__ float p[4];
    if (lane == 0) p[wv] = s2;
    __syncthreads();
    if (tid == 0) atomicAdd(&slots[j], p[0] + p[1] + p[2] + p[3]);
    // flush block partial to global, staggered across blocks to spread addresses
    int boff = (blockIdx.x * 7) & 1023;
    for (int i = tid; i < 1024; i += 256) {
        int c4 = (i + boff) & 1023;
        atomicAdd(&w[c4 * 4 + 0], w_s[0 * 1024 + c4]);
        atomicAdd(&w[c4 * 4 + 1], w_s[1 * 1024 + c4]);
        atomicAdd(&w[c4 * 4 + 2], w_s[2 * 1024 + c4]);
        atomicAdd(&w[c4 * 4 + 3], w_s[3 * 1024 + c4]);
    }
}

// r_{j+1} = w - alpha_j * v_j - beta_{j-1} * v_{j-1}   (v = r * rsqrt(norm2))
// norm2[j+1] += ||r_{j+1}||^2 (atomic). Also zeroes rp = next step's w-target.
__global__ __launch_bounds__(256) void finish_kernel(float* __restrict__ wt,
                                                     const float* __restrict__ rc,
                                                     float* __restrict__ rp,
                                                     float* __restrict__ slots,
                                                     int j) {
    int i = blockIdx.x * 256 + threadIdx.x;
    float a = slots[j];
    float n2j = fmaxf(slots[64 + j], 1e-30f);
    float n2m = fmaxf(slots[64 + j - 1], 1e-30f);
    float invj = rsqrtf(n2j);
    float cb = sqrtf(n2j / n2m);     // beta_{j-1} / ||r_{j-1}||
    float rn = wt[i] - a * invj * rc[i] - cb * rp[i];
    wt[i] = rn;
    rp[i] = 0.f;
    float p = rn * rn;
#pragma unroll
    for (int off = 32; off > 0; off >>= 1) p += __shfl_xor(p, off);
    __shared__ float part[4];
    int lane = threadIdx.x & 63, wq = threadIdx.x >> 6;
    if (lane == 0) part[wq] = p;
    __syncthreads();
    if (threadIdx.x == 0)
        atomicAdd(&slots[64 + j + 1], part[0] + part[1] + part[2] + part[3]);
}

// Largest eigenvalue of the t x t tridiagonal via Sturm bisection: 64 lanes
// test 64 shifts per round, 3 rounds -> resolution (range / 64^3).
__global__ void solve_kernel(const float* __restrict__ slots,
                             float* __restrict__ out, int t) {
    __shared__ float d_s[64], e2_s[64];
    int lane = threadIdx.x;
    d_s[lane] = (lane < t) ? slots[1 + lane] : 0.f;
    e2_s[lane] = (lane < t - 1) ? slots[64 + lane + 2] : 0.f;  // beta_{lane+1}^2
    __syncthreads();
    float e_here = sqrtf(e2_s[lane]);
    float e_prev = (lane > 0) ? sqrtf(e2_s[lane - 1]) : 0.f;
    float d = d_s[lane];
    float gersh = (lane < t) ? d + e_here + e_prev : 0.f;
    float dmax = (lane < t) ? d : 0.f;
#pragma unroll
    for (int off = 32; off > 0; off >>= 1) {
        gersh = fmaxf(gersh, __shfl_xor(gersh, off));
        dmax = fmaxf(dmax, __shfl_xor(dmax, off));
    }
    float lo = dmax, hi = gersh + 1e-3f;   // dmax <= lambda1 <= gersh
    for (int round = 0; round < 3; ++round) {
        float stepw = (hi - lo) * (1.f / 64.f);
        float x = lo + stepw * (lane + 1);
        double q = 1.0;
        int cnt = 0;
        for (int i = 0; i < t; ++i) {
            double qi = (double)d_s[i] - (double)x - ((i > 0) ? (double)e2_s[i - 1] / q : 0.0);
            if (fabs(qi) < 1e-300) qi = -1e-300;
            cnt += (qi < 0.0);
            q = qi;
        }
        // cnt(x) = #eigs < x;  cnt < t  <=>  lambda1 >= x
        unsigned long long m = __ballot(cnt < t);
        if (m) {
            int h = 63 - __clzll(m);
            lo = lo + stepw * (h + 1);
            hi = lo + stepw;
        } else {
            hi = lo + stepw;
        }
    }
    if (lane == 0) out[0] = 0.5f * (lo + hi);
}

extern "C" void kernel_launch(void* const* d_in, const int* in_sizes, int n_in,
                              void* d_out, int out_size, void* d_ws, size_t ws_size,
                              hipStream_t stream) {
    const float* A = (const float*)d_in[0];
    float* out = (float*)d_out;
    float* ws = (float*)d_ws;
    float* vb[3] = {ws, ws + 4096, ws + 8192};
    float* slots = ws + 12288;

    init_kernel<<<16, 256, 0, stream>>>(ws);

    const int T = T_STEPS;
    // rotation: step j reads rc = vb[(j+2)%3], rp = vb[(j+1)%3], writes wt = vb[j%3]
    // init made: r1 = vb[0] (j=1 rc -> (1+2)%3=0 ✓), r0 = vb[1], wt1 = vb[2] (j%3... )
    for (int j = 1; j <= T; ++j) {
        float* rc = vb[j % 3];          // r_j
        float* rp = vb[(j + 2) % 3];    // r_{j-1}
        float* wt = vb[(j + 1) % 3];    // accumulates w -> becomes r_{j+1}
        bmv_kernel<<<BMV_BLOCKS, 256, 0, stream>>>(A, rc, wt, slots, j);
        if (j < T)
            finish_kernel<<<16, 256, 0, stream>>>(wt, rc, rp, slots, j);
    }
    solve_kernel<<<1, 64, 0, stream>>>(slots, out, T);
}

// Round 3
// 874.171 us; speedup vs baseline: 7.5810x; 7.5810x over previous
//
#include <hip/hip_runtime.h>
#include <hip/hip_fp16.h>
#include <math.h>

// BatchSpectralLoss: out = lambda_max(A^T A), A = 8192x4096 fp32 (k==1).
// T-step Lanczos. Per step, ONE fused pass over A computes u=Av (never stored;
// alpha=||u||^2 via 1 atomic/block) and per-block partial w = A^T u slices
// held in REGISTERS (wave owns 512 cols, lane owns 8). No contended atomics:
// blocks write private partials; reduce_finish sums them and applies the
// Lanczos recurrence. A optionally cast to fp16 once (||dA|| -> dlambda ~28,
// threshold 476). Tridiagonal solved by Sturm bisection in one wave.
//
// ws float layout: vb0/vb1/vb2 at 0/4096/8192 (rotating residuals),
// slots at 12288 (alpha[j]=slots[j], norm2[j]=slots[64+j]),
// partials at 16384 (P x 4096), Ah (fp16 copy) at byte offset 16 MiB.

#define NROWS 8192
#define NCOLS 4096
#define T_STEPS 16
#define CHUNKS 512          // 512 chunks x 16 rows
#define RPC 16              // rows per chunk

__global__ __launch_bounds__(256) void init_kernel(float* __restrict__ ws) {
    int i = blockIdx.x * 256 + threadIdx.x;   // 0..4095
    float* r1 = ws;
    float* r0 = ws + 4096;
    float* slots = ws + 12288;
    unsigned h = (unsigned)i * 2654435761u;
    h ^= h >> 16; h *= 2246822519u; h ^= h >> 13;
    r1[i] = (h & 1u) ? 0.015625f : -0.015625f;   // +-1/64, unit norm
    r0[i] = 0.f;
    if (i < 128) slots[i] = (i == 64 || i == 65) ? 1.f : 0.f;
}

__global__ __launch_bounds__(256) void convert_kernel(const float* __restrict__ A,
                                                      __half* __restrict__ Ah) {
    const float4* A4 = (const float4*)A;
    float2* O2 = (float2*)Ah;
    for (int i = blockIdx.x * 256 + threadIdx.x; i < (NROWS * NCOLS / 4); i += 2048 * 256) {
        float4 f = A4[i];
        union { float2 f2; __half2 h2[2]; } u;
        u.h2[0] = __halves2half2(__float2half_rn(f.x), __float2half_rn(f.y));
        u.h2[1] = __halves2half2(__float2half_rn(f.z), __float2half_rn(f.w));
        O2[i] = u.f2;
    }
}

// ---- fused B-matvec, fp16 A.  512 threads = 8 waves; wave covers cols
// [wv*512, wv*512+512); lane owns 8 consecutive cols. Grid-stride over chunks.
__global__ __launch_bounds__(512, 4) void bmv_f16(const __half* __restrict__ Ah,
                                                  const float* __restrict__ rc,
                                                  float* __restrict__ partials,
                                                  float* __restrict__ slots,
                                                  int j, int P) {
    __shared__ float grid[8][16];
    int tid = threadIdx.x, lane = tid & 63, wv = tid >> 6;
    float inv = rsqrtf(fmaxf(slots[64 + j], 1e-30f));
    int colbase = wv * 512 + lane * 8;
    float vf[8];
    {
        const float4* r4 = (const float4*)(rc + colbase);
        float4 va = r4[0], vb = r4[1];
        vf[0] = va.x * inv; vf[1] = va.y * inv; vf[2] = va.z * inv; vf[3] = va.w * inv;
        vf[4] = vb.x * inv; vf[5] = vb.y * inv; vf[6] = vb.z * inv; vf[7] = vb.w * inv;
    }
    float wacc[8] = {0.f, 0.f, 0.f, 0.f, 0.f, 0.f, 0.f, 0.f};
    for (int chunk = blockIdx.x; chunk < CHUNKS; chunk += P) {
        __syncthreads();   // protect grid from previous iteration's readers
        const float4* Abase = (const float4*)(Ah + (size_t)chunk * RPC * NCOLS + colbase);
        float sp[RPC];
#pragma unroll
        for (int r = 0; r < RPC; ++r) {
            union { float4 f4; __half2 h2[4]; } u;
            u.f4 = Abase[r * (NCOLS / 8)];           // row stride: 4096 halves = 512 float4
            float2 p0 = __half22float2(u.h2[0]);
            float2 p1 = __half22float2(u.h2[1]);
            float2 p2 = __half22float2(u.h2[2]);
            float2 p3 = __half22float2(u.h2[3]);
            sp[r] = p0.x * vf[0] + p0.y * vf[1] + p1.x * vf[2] + p1.y * vf[3]
                  + p2.x * vf[4] + p2.y * vf[5] + p3.x * vf[6] + p3.y * vf[7];
        }
#pragma unroll
        for (int r = 0; r < RPC; ++r) {
#pragma unroll
            for (int off = 32; off > 0; off >>= 1) sp[r] += __shfl_xor(sp[r], off);
        }
        if (lane == 0) {
#pragma unroll
            for (int r = 0; r < RPC; ++r) grid[wv][r] = sp[r];
        }
        __syncthreads();
        float sval = 0.f;
        if (lane < RPC) {
#pragma unroll
            for (int w8 = 0; w8 < 8; ++w8) sval += grid[w8][lane];
        }
        if (wv == 0) {   // alpha += sum_r s_r^2 : one atomic per block per chunk
            float p = (lane < RPC) ? sval * sval : 0.f;
#pragma unroll
            for (int off = 8; off > 0; off >>= 1) p += __shfl_xor(p, off);
            if (lane == 0) atomicAdd(&slots[j], p);
        }
#pragma unroll
        for (int r = 0; r < RPC; ++r) {   // phase 2: reload (L2/L3-hot), accumulate
            float s = __shfl(sval, r);
            union { float4 f4; __half2 h2[4]; } u;
            u.f4 = Abase[r * (NCOLS / 8)];
            float2 p0 = __half22float2(u.h2[0]);
            float2 p1 = __half22float2(u.h2[1]);
            float2 p2 = __half22float2(u.h2[2]);
            float2 p3 = __half22float2(u.h2[3]);
            wacc[0] += s * p0.x; wacc[1] += s * p0.y; wacc[2] += s * p1.x; wacc[3] += s * p1.y;
            wacc[4] += s * p2.x; wacc[5] += s * p2.y; wacc[6] += s * p3.x; wacc[7] += s * p3.y;
        }
    }
    float4* pb = (float4*)(partials + (size_t)blockIdx.x * NCOLS + colbase);
    pb[0] = make_float4(wacc[0], wacc[1], wacc[2], wacc[3]);
    pb[1] = make_float4(wacc[4], wacc[5], wacc[6], wacc[7]);
}

// ---- fused B-matvec, fp32 A (fallback if ws too small for the fp16 copy).
// Lane owns cols {wv*512+lane*4..+3} and {wv*512+256+lane*4..+3} (coalesced).
__global__ __launch_bounds__(512, 4) void bmv_f32(const float* __restrict__ A,
                                                  const float* __restrict__ rc,
                                                  float* __restrict__ partials,
                                                  float* __restrict__ slots,
                                                  int j, int P) {
    __shared__ float grid[8][16];
    int tid = threadIdx.x, lane = tid & 63, wv = tid >> 6;
    float inv = rsqrtf(fmaxf(slots[64 + j], 1e-30f));
    float vf[8];
    {
        const float4* r4 = (const float4*)(rc + wv * 512);
        float4 va = r4[lane], vb = r4[64 + lane];
        vf[0] = va.x * inv; vf[1] = va.y * inv; vf[2] = va.z * inv; vf[3] = va.w * inv;
        vf[4] = vb.x * inv; vf[5] = vb.y * inv; vf[6] = vb.z * inv; vf[7] = vb.w * inv;
    }
    float wacc[8] = {0.f, 0.f, 0.f, 0.f, 0.f, 0.f, 0.f, 0.f};
    for (int chunk = blockIdx.x; chunk < CHUNKS; chunk += P) {
        __syncthreads();
        const float4* Abase = (const float4*)(A + (size_t)chunk * RPC * NCOLS + wv * 512);
        float sp[RPC];
#pragma unroll
        for (int r = 0; r < RPC; ++r) {
            float4 a0 = Abase[r * (NCOLS / 4) + lane];
            float4 a1 = Abase[r * (NCOLS / 4) + 64 + lane];
            sp[r] = a0.x * vf[0] + a0.y * vf[1] + a0.z * vf[2] + a0.w * vf[3]
                  + a1.x * vf[4] + a1.y * vf[5] + a1.z * vf[6] + a1.w * vf[7];
        }
#pragma unroll
        for (int r = 0; r < RPC; ++r) {
#pragma unroll
            for (int off = 32; off > 0; off >>= 1) sp[r] += __shfl_xor(sp[r], off);
        }
        if (lane == 0) {
#pragma unroll
            for (int r = 0; r < RPC; ++r) grid[wv][r] = sp[r];
        }
        __syncthreads();
        float sval = 0.f;
        if (lane < RPC) {
#pragma unroll
            for (int w8 = 0; w8 < 8; ++w8) sval += grid[w8][lane];
        }
        if (wv == 0) {
            float p = (lane < RPC) ? sval * sval : 0.f;
#pragma unroll
            for (int off = 8; off > 0; off >>= 1) p += __shfl_xor(p, off);
            if (lane == 0) atomicAdd(&slots[j], p);
        }
#pragma unroll
        for (int r = 0; r < RPC; ++r) {
            float s = __shfl(sval, r);
            float4 a0 = Abase[r * (NCOLS / 4) + lane];
            float4 a1 = Abase[r * (NCOLS / 4) + 64 + lane];
            wacc[0] += s * a0.x; wacc[1] += s * a0.y; wacc[2] += s * a0.z; wacc[3] += s * a0.w;
            wacc[4] += s * a1.x; wacc[5] += s * a1.y; wacc[6] += s * a1.z; wacc[7] += s * a1.w;
        }
    }
    float4* pb = (float4*)(partials + (size_t)blockIdx.x * NCOLS + wv * 512);
    pb[lane] = make_float4(wacc[0], wacc[1], wacc[2], wacc[3]);
    pb[64 + lane] = make_float4(wacc[4], wacc[5], wacc[6], wacc[7]);
}

// ---- sum P partials per column + Lanczos recurrence:
// r_{j+1} = w - alpha_j v_j - beta_{j-1} v_{j-1};  norm2[j+1] += ||r||^2.
__global__ __launch_bounds__(512) void reduce_finish(const float* __restrict__ partials,
                                                     float* __restrict__ wt,
                                                     const float* __restrict__ rc,
                                                     const float* __restrict__ rp,
                                                     float* __restrict__ slots,
                                                     int j, int P) {
    __shared__ float red[8][64];
    int tid = threadIdx.x, l = tid & 63, q = tid >> 6;
    int c = blockIdx.x * 64 + l;
    int nb = P >> 3;
    float s = 0.f;
    const float* p0 = partials + (size_t)q * nb * NCOLS + c;
    for (int b = 0; b < nb; ++b) s += p0[(size_t)b * NCOLS];
    red[q][l] = s;
    __syncthreads();
    if (tid < 64) {
        float w = 0.f;
#pragma unroll
        for (int qq = 0; qq < 8; ++qq) w += red[qq][tid];
        float a = slots[j];
        float n2j = fmaxf(slots[64 + j], 1e-30f);
        float n2m = fmaxf(slots[64 + j - 1], 1e-30f);
        float invj = rsqrtf(n2j);
        float cb = sqrtf(n2j / n2m);             // beta_{j-1}/||r_{j-1}||
        float rn = w - a * invj * rc[c] - cb * rp[c];
        wt[c] = rn;
        float p = rn * rn;
#pragma unroll
        for (int off = 32; off > 0; off >>= 1) p += __shfl_xor(p, off);
        if (tid == 0) atomicAdd(&slots[64 + j + 1], p);
    }
}

// ---- largest eigenvalue of t x t tridiagonal via Sturm bisection (1 wave).
__global__ void solve_kernel(const float* __restrict__ slots,
                             float* __restrict__ out, int t) {
    __shared__ float d_s[64], e2_s[64];
    int lane = threadIdx.x;
    d_s[lane] = (lane < t) ? slots[1 + lane] : 0.f;
    e2_s[lane] = (lane < t - 1) ? slots[64 + lane + 2] : 0.f;
    __syncthreads();
    float e_here = sqrtf(e2_s[lane]);
    float e_prev = (lane > 0) ? sqrtf(e2_s[lane - 1]) : 0.f;
    float d = d_s[lane];
    float gersh = (lane < t) ? d + e_here + e_prev : 0.f;
    float dmax = (lane < t) ? d : 0.f;
#pragma unroll
    for (int off = 32; off > 0; off >>= 1) {
        gersh = fmaxf(gersh, __shfl_xor(gersh, off));
        dmax = fmaxf(dmax, __shfl_xor(dmax, off));
    }
    float lo = dmax, hi = gersh + 1e-3f;
    for (int round = 0; round < 3; ++round) {
        float stepw = (hi - lo) * (1.f / 64.f);
        float x = lo + stepw * (lane + 1);
        double qv = 1.0;
        int cnt = 0;
        for (int i = 0; i < t; ++i) {
            double qi = (double)d_s[i] - (double)x - ((i > 0) ? (double)e2_s[i - 1] / qv : 0.0);
            if (fabs(qi) < 1e-300) qi = -1e-300;
            cnt += (qi < 0.0);
            qv = qi;
        }
        unsigned long long m = __ballot(cnt < t);
        if (m) {
            int h = 63 - __clzll(m);
            lo = lo + stepw * (h + 1);
            hi = lo + stepw;
        } else {
            hi = lo + stepw;
        }
    }
    if (lane == 0) out[0] = 0.5f * (lo + hi);
}

extern "C" void kernel_launch(void* const* d_in, const int* in_sizes, int n_in,
                              void* d_out, int out_size, void* d_ws, size_t ws_size,
                              hipStream_t stream) {
    const float* A = (const float*)d_in[0];
    float* out = (float*)d_out;
    float* ws = (float*)d_ws;
    float* vb[3] = {ws, ws + 4096, ws + 8192};
    float* slots = ws + 12288;
    float* partials = ws + 16384;
    __half* Ah = (__half*)((char*)d_ws + (size_t)16 * 1024 * 1024);

    const size_t need_f16 = (size_t)16 * 1024 * 1024 + sizeof(__half) * (size_t)NROWS * NCOLS;
    bool use_f16 = (ws_size >= need_f16);
    int P;
    if (use_f16) {
        P = 512;
    } else {
        size_t avail = (ws_size > 16384u * 4u) ? ws_size - 16384u * 4u : 0;
        int pmax = (int)(avail / ((size_t)NCOLS * 4));
        P = pmax >= 512 ? 512 : (pmax / 8) * 8;
        if (P < 8) P = 8;
    }

    init_kernel<<<16, 256, 0, stream>>>(ws);
    if (use_f16) convert_kernel<<<2048, 256, 0, stream>>>(A, Ah);

    const int T = T_STEPS;
    for (int j = 1; j <= T; ++j) {
        float* rc = vb[j % 3];
        float* rp = vb[(j + 2) % 3];
        float* wt = vb[(j + 1) % 3];
        if (use_f16)
            bmv_f16<<<P, 512, 0, stream>>>(Ah, rc, partials, slots, j, P);
        else
            bmv_f32<<<P, 512, 0, stream>>>(A, rc, partials, slots, j, P);
        if (j < T)
            reduce_finish<<<64, 512, 0, stream>>>(partials, wt, rc, rp, slots, j, P);
    }
    solve_kernel<<<1, 64, 0, stream>>>(slots, out, T);
}